// Round 6
// baseline (109.207 us; speedup 1.0000x reference)
//
#include <hip/hip_runtime.h>

// Tiny MLP 2->15->15->15->1 (SiLU x3, sigmoid), N=2^21 rows, fp32 in/out.
//
// Round-6: occupancy-first. __launch_bounds__(256,8) caps VGPR at 64 ->
// 8 waves/SIMD (r5's 4-tile body sat at ~100 VGPR -> 4 waves, latency
// exposed). Slim 2-tile body:
//  - interleaved tile pairing (tile0=even samples, tile1=odd): one
//    float4 x-load and one float2 store per lane
//  - MFMA feature-major chaining (16x16x16 f16: D-layout == B-layout,
//    zero cross-lane, zero LDS)
//  - packed fp32 VALU, paired-reciprocal SiLU, v_cvt_pkrtz packing

using half4   = __attribute__((ext_vector_type(4))) _Float16;
using half2v  = __attribute__((ext_vector_type(2))) _Float16;
using fp16x2  = __attribute__((ext_vector_type(2))) __fp16;
using floatx4 = __attribute__((ext_vector_type(4))) float;
using v2f     = __attribute__((ext_vector_type(2))) float;

__device__ __forceinline__ v2f sigmoid2(v2f x) {
    // den = 1 + exp(-x); paired reciprocal: one v_rcp per 2 elements
    v2f den;
    den[0] = 1.0f + __expf(-x[0]);
    den[1] = 1.0f + __expf(-x[1]);
    const float r = __builtin_amdgcn_rcpf(den[0] * den[1]);
    return (v2f){den[1] * r, den[0] * r};
}

__device__ __forceinline__ half2v silu2h(v2f x) {
    v2f s = x * sigmoid2(x);                            // v_pk_mul_f32
    fp16x2 p = __builtin_amdgcn_cvt_pkrtz(s[0], s[1]);  // one cvt+pack
    return __builtin_bit_cast(half2v, p);
}

__global__ __launch_bounds__(256, 8) void mlp_mfma(
    const float* __restrict__ x,
    const float* __restrict__ W1, const float* __restrict__ b1,
    const float* __restrict__ W2, const float* __restrict__ b2,
    const float* __restrict__ W3, const float* __restrict__ b3,
    const float* __restrict__ W4, const float* __restrict__ b4,
    float* __restrict__ out, int N)
{
    const int lane = threadIdx.x & 63;
    const int col  = lane & 15;   // sample slot (B/D col) and A-row m
    const int quad = lane >> 4;   // k-group

    // ---- constant per-lane fragments (tiny, L1/L2-cached) ----
    half4 A2, A3, A4;                 // A[m][k] = W[k][m]
    v2f w10p[2], w11p[2], vb1p[2];    // layer-1 weights packed across i-pairs
    v2f vb2p[2], vb3p[2];             // bias packed across D-row reg pairs
    #pragma unroll
    for (int i = 0; i < 4; ++i) {
        const int k    = quad * 4 + i;   // input-feature index
        const int m    = col;            // output-feature (A row)
        const bool kin = (k < 15);
        A2[i] = (_Float16)((kin && m < 15) ? W2[k * 15 + m] : 0.0f);
        A3[i] = (_Float16)((kin && m < 15) ? W3[k * 15 + m] : 0.0f);
        A4[i] = (_Float16)((kin && m == 0) ? W4[k]          : 0.0f);
        w10p[i >> 1][i & 1] = kin ? W1[0 * 15 + k] : 0.0f;
        w11p[i >> 1][i & 1] = kin ? W1[1 * 15 + k] : 0.0f;
        vb1p[i >> 1][i & 1] = kin ? b1[k] : 0.0f;
        const int mq = quad * 4 + i;     // D row held in reg i
        vb2p[i >> 1][i & 1] = (mq < 15) ? b2[mq] : 0.0f;
        vb3p[i >> 1][i & 1] = (mq < 15) ? b3[mq] : 0.0f;
    }
    const float b4s = b4[0];
    const floatx4 zero = {0.f, 0.f, 0.f, 0.f};

    const int wave    = (blockIdx.x * blockDim.x + threadIdx.x) >> 6;
    const int nwaves  = (gridDim.x * blockDim.x) >> 6;
    const int nchunks = N >> 5;        // 32 samples per iteration

    for (int q = wave; q < nchunks; q += nwaves) {
        const int base = q * 32;
        // interleaved pairing: tile0 = even samples, tile1 = odd samples.
        // lane reads both x-rows of its sample pair as one aligned float4:
        // {x0_even, x1_even, x0_odd, x1_odd}
        const float4 xv = *reinterpret_cast<const float4*>(x + 2 * (base + 2 * col));

        // ---- layer 1: 2 -> 15, SiLU, build B fragments ----
        half4 B0, B1v;
        #pragma unroll
        for (int j = 0; j < 2; ++j) {         // j indexes reg pairs (i=2j,2j+1)
            v2f a0 = w10p[j] * xv.x + (w11p[j] * xv.y + vb1p[j]);
            v2f a1 = w10p[j] * xv.z + (w11p[j] * xv.w + vb1p[j]);
            half2v p0 = silu2h(a0);
            half2v p1 = silu2h(a1);
            B0[2*j]  = p0[0]; B0[2*j+1]  = p0[1];
            B1v[2*j] = p1[0]; B1v[2*j+1] = p1[1];
        }

        // ---- layer 2 (MFMA) + bias/SiLU ----
        floatx4 d0 = __builtin_amdgcn_mfma_f32_16x16x16f16(A2, B0,  zero, 0, 0, 0);
        floatx4 d1 = __builtin_amdgcn_mfma_f32_16x16x16f16(A2, B1v, zero, 0, 0, 0);
        #pragma unroll
        for (int j = 0; j < 2; ++j) {
            v2f t0 = (v2f){d0[2*j], d0[2*j+1]} + vb2p[j];
            v2f t1 = (v2f){d1[2*j], d1[2*j+1]} + vb2p[j];
            half2v p0 = silu2h(t0);
            half2v p1 = silu2h(t1);
            B0[2*j]  = p0[0]; B0[2*j+1]  = p0[1];
            B1v[2*j] = p1[0]; B1v[2*j+1] = p1[1];
        }

        // ---- layer 3 ----
        d0 = __builtin_amdgcn_mfma_f32_16x16x16f16(A3, B0,  zero, 0, 0, 0);
        d1 = __builtin_amdgcn_mfma_f32_16x16x16f16(A3, B1v, zero, 0, 0, 0);
        #pragma unroll
        for (int j = 0; j < 2; ++j) {
            v2f t0 = (v2f){d0[2*j], d0[2*j+1]} + vb3p[j];
            v2f t1 = (v2f){d1[2*j], d1[2*j+1]} + vb3p[j];
            half2v p0 = silu2h(t0);
            half2v p1 = silu2h(t1);
            B0[2*j]  = p0[0]; B0[2*j+1]  = p0[1];
            B1v[2*j] = p1[0]; B1v[2*j+1] = p1[1];
        }

        // ---- layer 4: 15 -> 1, sigmoid ----
        d0 = __builtin_amdgcn_mfma_f32_16x16x16f16(A4, B0,  zero, 0, 0, 0);
        d1 = __builtin_amdgcn_mfma_f32_16x16x16f16(A4, B1v, zero, 0, 0, 0);

        v2f o = (v2f){d0[0], d1[0]} + b4s;   // {even, odd} for sample pair
        v2f s = sigmoid2(o);
        if (lane < 16) {   // quad 0 / reg 0 holds D row 0
            *reinterpret_cast<float2*>(out + base + 2 * lane) = (float2){s[0], s[1]};
        }
    }
}

extern "C" void kernel_launch(void* const* d_in, const int* in_sizes, int n_in,
                              void* d_out, int out_size, void* d_ws, size_t ws_size,
                              hipStream_t stream) {
    const float* x  = (const float*)d_in[0];
    const float* W1 = (const float*)d_in[1];
    const float* b1 = (const float*)d_in[2];
    const float* W2 = (const float*)d_in[3];
    const float* b2 = (const float*)d_in[4];
    const float* W3 = (const float*)d_in[5];
    const float* b3 = (const float*)d_in[6];
    const float* W4 = (const float*)d_in[7];
    const float* b4 = (const float*)d_in[8];
    float* out = (float*)d_out;

    const int N = in_sizes[0] / 2;   // rows
    const int blocks = 2048;         // 8 blocks/CU, 32 waves/CU at VGPR<=64
    mlp_mfma<<<blocks, 256, 0, stream>>>(x, W1, b1, W2, b2, W3, b3, W4, b4, out, N);
}

// Round 7
// 102.279 us; speedup vs baseline: 1.0677x; 1.0677x over previous
//
#include <hip/hip_runtime.h>

// Tiny MLP 2->15->15->15->1 (SiLU x3, sigmoid), N=2^21 rows, fp32 in/out.
//
// Round-7: ZERO transcendentals in the hot loop. sigmoid via LDS lookup
// table (4096 x f32, nearest, [-16,16] step 1/128; sigma-err<=9.8e-4,
// silu-err<=8.7e-4). Built once per block. SiLU = x * lut(x): 5 full-rate
// VALU + 1 ds_read per element; 8 independent lookups per layer overlap.
// Matmuls stay on the MFMA pipe (16x16x16 f16, feature-major chaining:
// D-layout == B-layout, zero cross-lane). 16KB LDS -> still 8 blocks/CU.

using half4   = __attribute__((ext_vector_type(4))) _Float16;
using half2v  = __attribute__((ext_vector_type(2))) _Float16;
using fp16x2  = __attribute__((ext_vector_type(2))) __fp16;
using floatx4 = __attribute__((ext_vector_type(4))) float;
using v2f     = __attribute__((ext_vector_type(2))) float;

#define LUT_N     4096
#define LUT_SCALE 128.0f       // entries per unit x
#define LUT_BIAS  2048.5f      // center + 0.5 for nearest rounding

__device__ __forceinline__ float sig_lut(float xx, const float* __restrict__ lut) {
    float t = fmaf(xx, LUT_SCALE, LUT_BIAS);            // v_fma
    t = fminf(fmaxf(t, 0.0f), 4095.0f);                 // v_med3
    return lut[(int)t];                                 // v_cvt + v_lshl + ds_read_b32
}

__device__ __forceinline__ half2v silu2h(v2f xx, const float* __restrict__ lut) {
    float s0 = xx[0] * sig_lut(xx[0], lut);
    float s1 = xx[1] * sig_lut(xx[1], lut);
    fp16x2 p = __builtin_amdgcn_cvt_pkrtz(s0, s1);      // one cvt+pack
    return __builtin_bit_cast(half2v, p);
}

__global__ __launch_bounds__(256, 8) void mlp_mfma(
    const float* __restrict__ x,
    const float* __restrict__ W1, const float* __restrict__ b1,
    const float* __restrict__ W2, const float* __restrict__ b2,
    const float* __restrict__ W3, const float* __restrict__ b3,
    const float* __restrict__ W4, const float* __restrict__ b4,
    float* __restrict__ out, int N)
{
    __shared__ float lut[LUT_N];

    const int tid = threadIdx.x;
    // ---- build sigmoid LUT (once per block; 16 exp per thread) ----
    #pragma unroll
    for (int i = tid; i < LUT_N; i += 256) {
        float v = ((float)i - 2048.0f) * (1.0f / LUT_SCALE);
        lut[i] = __builtin_amdgcn_rcpf(1.0f + __expf(-v));
    }

    const int lane = tid & 63;
    const int col  = lane & 15;   // sample slot (B/D col) and A-row m
    const int quad = lane >> 4;   // k-group

    // ---- constant per-lane fragments (tiny, L1/L2-cached) ----
    half4 A2, A3, A4;                 // A[m][k] = W[k][m]
    v2f w10p[2], w11p[2], vb1p[2];    // layer-1 weights packed across i-pairs
    v2f vb2p[2], vb3p[2];             // bias packed across D-row reg pairs
    #pragma unroll
    for (int i = 0; i < 4; ++i) {
        const int k    = quad * 4 + i;   // input-feature index
        const int m    = col;            // output-feature (A row)
        const bool kin = (k < 15);
        A2[i] = (_Float16)((kin && m < 15) ? W2[k * 15 + m] : 0.0f);
        A3[i] = (_Float16)((kin && m < 15) ? W3[k * 15 + m] : 0.0f);
        A4[i] = (_Float16)((kin && m == 0) ? W4[k]          : 0.0f);
        w10p[i >> 1][i & 1] = kin ? W1[0 * 15 + k] : 0.0f;
        w11p[i >> 1][i & 1] = kin ? W1[1 * 15 + k] : 0.0f;
        vb1p[i >> 1][i & 1] = kin ? b1[k] : 0.0f;
        const int mq = quad * 4 + i;     // D row held in reg i
        vb2p[i >> 1][i & 1] = (mq < 15) ? b2[mq] : 0.0f;
        vb3p[i >> 1][i & 1] = (mq < 15) ? b3[mq] : 0.0f;
    }
    const float b4s = b4[0];
    const floatx4 zero = {0.f, 0.f, 0.f, 0.f};

    __syncthreads();   // LUT ready

    const int wave    = (blockIdx.x * blockDim.x + tid) >> 6;
    const int nwaves  = (gridDim.x * blockDim.x) >> 6;
    const int nchunks = N >> 5;        // 32 samples per iteration

    for (int q = wave; q < nchunks; q += nwaves) {
        const int base = q * 32;
        // interleaved pairing: tile0 = even samples, tile1 = odd samples.
        // one aligned float4: {x0_even, x1_even, x0_odd, x1_odd}
        const float4 xv = *reinterpret_cast<const float4*>(x + 2 * (base + 2 * col));

        // ---- layer 1: 2 -> 15, SiLU, build B fragments ----
        half4 B0, B1v;
        #pragma unroll
        for (int j = 0; j < 2; ++j) {         // j indexes reg pairs (i=2j,2j+1)
            v2f a0 = w10p[j] * xv.x + (w11p[j] * xv.y + vb1p[j]);
            v2f a1 = w10p[j] * xv.z + (w11p[j] * xv.w + vb1p[j]);
            half2v p0 = silu2h(a0, lut);
            half2v p1 = silu2h(a1, lut);
            B0[2*j]  = p0[0]; B0[2*j+1]  = p0[1];
            B1v[2*j] = p1[0]; B1v[2*j+1] = p1[1];
        }

        // ---- layer 2 (MFMA) + bias/SiLU ----
        floatx4 d0 = __builtin_amdgcn_mfma_f32_16x16x16f16(A2, B0,  zero, 0, 0, 0);
        floatx4 d1 = __builtin_amdgcn_mfma_f32_16x16x16f16(A2, B1v, zero, 0, 0, 0);
        #pragma unroll
        for (int j = 0; j < 2; ++j) {
            v2f t0 = (v2f){d0[2*j], d0[2*j+1]} + vb2p[j];
            v2f t1 = (v2f){d1[2*j], d1[2*j+1]} + vb2p[j];
            half2v p0 = silu2h(t0, lut);
            half2v p1 = silu2h(t1, lut);
            B0[2*j]  = p0[0]; B0[2*j+1]  = p0[1];
            B1v[2*j] = p1[0]; B1v[2*j+1] = p1[1];
        }

        // ---- layer 3 ----
        d0 = __builtin_amdgcn_mfma_f32_16x16x16f16(A3, B0,  zero, 0, 0, 0);
        d1 = __builtin_amdgcn_mfma_f32_16x16x16f16(A3, B1v, zero, 0, 0, 0);
        #pragma unroll
        for (int j = 0; j < 2; ++j) {
            v2f t0 = (v2f){d0[2*j], d0[2*j+1]} + vb3p[j];
            v2f t1 = (v2f){d1[2*j], d1[2*j+1]} + vb3p[j];
            half2v p0 = silu2h(t0, lut);
            half2v p1 = silu2h(t1, lut);
            B0[2*j]  = p0[0]; B0[2*j+1]  = p0[1];
            B1v[2*j] = p1[0]; B1v[2*j+1] = p1[1];
        }

        // ---- layer 4: 15 -> 1, sigmoid (via LUT) ----
        d0 = __builtin_amdgcn_mfma_f32_16x16x16f16(A4, B0,  zero, 0, 0, 0);
        d1 = __builtin_amdgcn_mfma_f32_16x16x16f16(A4, B1v, zero, 0, 0, 0);

        const float s0 = sig_lut(d0[0] + b4s, lut);   // even sample
        const float s1 = sig_lut(d1[0] + b4s, lut);   // odd sample
        if (lane < 16) {   // quad 0 / reg 0 holds D row 0
            *reinterpret_cast<float2*>(out + base + 2 * lane) = (float2){s0, s1};
        }
    }
}

extern "C" void kernel_launch(void* const* d_in, const int* in_sizes, int n_in,
                              void* d_out, int out_size, void* d_ws, size_t ws_size,
                              hipStream_t stream) {
    const float* x  = (const float*)d_in[0];
    const float* W1 = (const float*)d_in[1];
    const float* b1 = (const float*)d_in[2];
    const float* W2 = (const float*)d_in[3];
    const float* b2 = (const float*)d_in[4];
    const float* W3 = (const float*)d_in[5];
    const float* b3 = (const float*)d_in[6];
    const float* W4 = (const float*)d_in[7];
    const float* b4 = (const float*)d_in[8];
    float* out = (float*)d_out;

    const int N = in_sizes[0] / 2;   // rows
    const int blocks = 2048;         // 8 blocks/CU; 16KB LDS -> 128KB/CU, fits
    mlp_mfma<<<blocks, 256, 0, stream>>>(x, W1, b1, W2, b2, W3, b3, W4, b4, out, N);
}